// Round 6
// baseline (335.836 us; speedup 1.0000x reference)
//
#include <hip/hip_runtime.h>

#define NCELL 4096

__device__ __forceinline__ int cell_of(float x0, float x1, float x2) {
    int i0 = (int)(x0 / 0.1875f + 8.0f);
    int i1 = (int)(x1 / 0.1875f + 8.0f);
    int i2 = (int)(x2 / 0.1875f + 8.0f);
    i0 = i0 < 0 ? 0 : (i0 > 15 ? 15 : i0);
    i1 = i1 < 0 ? 0 : (i1 > 15 ? 15 : i1);
    i2 = i2 < 0 ? 0 : (i2 > 15 ? 15 : i2);
    return (i0 * 16 + i1) * 16 + i2;
}

__global__ void k_count(const float* __restrict__ xs, int* __restrict__ counts,
                        float* __restrict__ out, int P) {
    int p = blockIdx.x * blockDim.x + threadIdx.x;
    if (p >= P) return;
    float x0 = xs[p * 3 + 0], x1 = xs[p * 3 + 1], x2 = xs[p * 3 + 2];
    bool m = (fabsf(x0) < 1.5f) && (fabsf(x1) < 1.5f) && (fabsf(x2) < 1.5f);
    if (m) {
        atomicAdd(&counts[cell_of(x0, x1, x2)], 1);
    } else {
        out[p * 3 + 0] = 0.0f;
        out[p * 3 + 1] = 0.0f;
        out[p * 3 + 2] = 0.0f;
        out[3 * P + p] = 0.0f;
    }
}

__global__ void k_scan(const int* __restrict__ counts, int* __restrict__ offsets,
                       int* __restrict__ cursor) {
    int l = threadIdx.x;
    int base = l * 64;
    int s = 0;
    for (int k = 0; k < 64; k++) s += counts[base + k];
    int incl = s;
    for (int d = 1; d < 64; d <<= 1) {
        int v = __shfl_up(incl, d, 64);
        if (l >= d) incl += v;
    }
    int run = incl - s;
    for (int k = 0; k < 64; k++) {
        offsets[base + k] = run;
        cursor[base + k] = run;
        run += counts[base + k];
    }
    if (l == 63) offsets[4096] = run;
}

__global__ void k_scatter(const float* __restrict__ xs, int* __restrict__ cursor,
                          int* __restrict__ sorted, int P) {
    int p = blockIdx.x * blockDim.x + threadIdx.x;
    if (p >= P) return;
    float x0 = xs[p * 3 + 0], x1 = xs[p * 3 + 1], x2 = xs[p * 3 + 2];
    bool m = (fabsf(x0) < 1.5f) && (fabsf(x1) < 1.5f) && (fabsf(x2) < 1.5f);
    if (!m) return;
    int c = cell_of(x0, x1, x2);
    int pos = atomicAdd(&cursor[c], 1);
    sorted[pos] = p;
}

// 16-wide row FMA from a wave-uniform GLOBAL row pointer -> scalar loads
// (s_load) + v_fmac with SGPR operand. No LDS pipe involvement.
#define ROW16G(ACC, RP, E)                                                 \
    {                                                                      \
        float _e = (E);                                                    \
        const float* _wr = (RP);                                           \
        _Pragma("unroll") for (int _o = 0; _o < 16; _o++)                  \
            ACC[_o] = fmaf(_e, _wr[_o], ACC[_o]);                          \
    }

// One block (2 waves, 128 thr) per cell. Wave w computes output columns
// [16w,16w+16). Weights read via wave-uniform scalar loads (K$/L2/L3);
// activations in per-lane LDS slots (stride 33 -> 2-way alias, free).
__global__ void __launch_bounds__(128) k_mlp(
    const float* __restrict__ xs, const float* __restrict__ dvs,
    const float* __restrict__ w1, const float* __restrict__ b1,
    const float* __restrict__ w2, const float* __restrict__ b2,
    const float* __restrict__ w3, const float* __restrict__ b3,
    const float* __restrict__ w4, const float* __restrict__ b4,
    const float* __restrict__ w5, const float* __restrict__ b5,
    const int* __restrict__ offsets, const int* __restrict__ sorted,
    float* __restrict__ out, int P) {
    __shared__ float act[64 * 33];
    int cell = blockIdx.x;
    int start = offsets[cell], end = offsets[cell + 1];
    if (start >= end) return;
    int tid = threadIdx.x;
    int lane = tid & 63;
    int wid = tid >> 6;
    int wo = wid << 4;

    // Wave-uniform global bases, pre-offset to this wave's output columns.
    const float* W1 = w1 + (size_t)cell * 2016 + wo;  // row stride 32
    const float* B1 = b1 + (size_t)cell * 32 + wo;
    const float* W2 = w2 + (size_t)cell * 1056 + wo;  // row stride 33
    const float* B2 = b2 + (size_t)cell * 33 + wo;
    const float* W3 = w3 + (size_t)cell * 1024 + wo;  // row stride 32
    const float* B3 = b3 + (size_t)cell * 32 + wo;
    const float* W4 = w4 + (size_t)cell * 1888 + wo;  // row stride 32
    const float* B4 = b4 + (size_t)cell * 32 + wo;
    const float* W5 = w5 + (size_t)cell * 96;         // 32x3
    const float* B5 = b5 + (size_t)cell * 3;

    float* al = &act[lane * 33];

    for (int t0 = start; t0 < end; t0 += 64) {
        __syncthreads();  // protect act vs previous iter's tail reads
        int t = t0 + lane;
        bool valid = t < end;
        int idx = sorted[valid ? t : start];

        float x0 = xs[idx * 3 + 0], x1 = xs[idx * 3 + 1], x2 = xs[idx * 3 + 2];
        float d0 = dvs[idx * 3 + 0], d1 = dvs[idx * 3 + 1], d2 = dvs[idx * 3 + 2];

        float acc[17];
        float sigma = 0.0f;

        // ---- layer 1: 63 -> 32 (this wave: 16), relu; pos-enc fused
#pragma unroll
        for (int o = 0; o < 16; o++) acc[o] = B1[o];
        ROW16G(acc, W1 + 0 * 32, x0)
        ROW16G(acc, W1 + 1 * 32, x1)
        ROW16G(acc, W1 + 2 * 32, x2)
        float pw = 1.0f;
#pragma unroll 2
        for (int j = 0; j < 10; j++) {
            float a0 = pw * x0, a1 = pw * x1, a2 = pw * x2;
            const float* rb = W1 + (3 + 6 * j) * 32;
            ROW16G(acc, rb + 0, __sinf(a0))
            ROW16G(acc, rb + 32, __sinf(a1))
            ROW16G(acc, rb + 64, __sinf(a2))
            ROW16G(acc, rb + 96, __cosf(a0))
            ROW16G(acc, rb + 128, __cosf(a1))
            ROW16G(acc, rb + 160, __cosf(a2))
            pw *= 2.0f;
        }
#pragma unroll
        for (int o = 0; o < 16; o++) al[wo + o] = fmaxf(acc[o], 0.0f);
        __syncthreads();  // L1 act visible

        // ---- layer 2: 32 -> 33; wave w computes cols [16w, 16w+17)
        float g[17];
#pragma unroll
        for (int k = 0; k < 17; k++) g[k] = B2[k];
#pragma unroll 2
        for (int i = 0; i < 32; i++) {
            float e = al[i];
            const float* wr = W2 + i * 33;
#pragma unroll
            for (int k = 0; k < 17; k++) g[k] = fmaf(e, wr[k], g[k]);
        }
        __syncthreads();  // all act reads done before overwrite
        if (wid == 0) {
            sigma = fmaxf(g[0], 0.0f);
#pragma unroll
            for (int k = 1; k < 17; k++) al[k - 1] = fmaxf(g[k], 0.0f);
        } else {
            // col 16 written by both waves with bit-identical value (same
            // accumulation order) -- benign.
#pragma unroll
            for (int k = 0; k < 17; k++) al[15 + k] = fmaxf(g[k], 0.0f);
        }
        __syncthreads();

        // ---- layer 3: 32 -> 32, no activation
#pragma unroll
        for (int o = 0; o < 16; o++) acc[o] = B3[o];
#pragma unroll 2
        for (int i = 0; i < 32; i++) {
            float e = al[i];
            ROW16G(acc, W3 + i * 32, e)
        }
        __syncthreads();
#pragma unroll
        for (int o = 0; o < 16; o++) al[wo + o] = acc[o];
        __syncthreads();

        // ---- layer 4: 59 -> 32, relu; dir-enc fused
#pragma unroll
        for (int o = 0; o < 16; o++) acc[o] = B4[o];
#pragma unroll 2
        for (int i = 0; i < 32; i++) {
            float e = al[i];
            ROW16G(acc, W4 + i * 32, e)
        }
        __syncthreads();  // act reads done
        ROW16G(acc, W4 + 32 * 32, d0)
        ROW16G(acc, W4 + 33 * 32, d1)
        ROW16G(acc, W4 + 34 * 32, d2)
        pw = 1.0f;
#pragma unroll 2
        for (int j = 0; j < 4; j++) {
            float a0 = pw * d0, a1 = pw * d1, a2 = pw * d2;
            const float* rb = W4 + (35 + 6 * j) * 32;
            ROW16G(acc, rb + 0, __sinf(a0))
            ROW16G(acc, rb + 32, __sinf(a1))
            ROW16G(acc, rb + 64, __sinf(a2))
            ROW16G(acc, rb + 96, __cosf(a0))
            ROW16G(acc, rb + 128, __cosf(a1))
            ROW16G(acc, rb + 160, __cosf(a2))
            pw *= 2.0f;
        }
#pragma unroll
        for (int o = 0; o < 16; o++) al[wo + o] = fmaxf(acc[o], 0.0f);
        __syncthreads();

        // ---- layer 5: 32 -> 3, sigmoid (wave 0 only)
        if (wid == 0) {
            float c0 = B5[0], c1 = B5[1], c2 = B5[2];
#pragma unroll 4
            for (int i = 0; i < 32; i++) {
                float e = al[i];
                c0 = fmaf(e, W5[i * 3 + 0], c0);
                c1 = fmaf(e, W5[i * 3 + 1], c1);
                c2 = fmaf(e, W5[i * 3 + 2], c2);
            }
            if (valid) {
                out[idx * 3 + 0] = 1.0f / (1.0f + __expf(-c0));
                out[idx * 3 + 1] = 1.0f / (1.0f + __expf(-c1));
                out[idx * 3 + 2] = 1.0f / (1.0f + __expf(-c2));
                out[3 * P + idx] = sigma;
            }
        }
    }
}

extern "C" void kernel_launch(void* const* d_in, const int* in_sizes, int n_in,
                              void* d_out, int out_size, void* d_ws, size_t ws_size,
                              hipStream_t stream) {
    const float* xs = (const float*)d_in[0];
    const float* dv = (const float*)d_in[1];
    const float* w1 = (const float*)d_in[2];
    const float* b1 = (const float*)d_in[3];
    const float* w2 = (const float*)d_in[4];
    const float* b2 = (const float*)d_in[5];
    const float* w3 = (const float*)d_in[6];
    const float* b3 = (const float*)d_in[7];
    const float* w4 = (const float*)d_in[8];
    const float* b4 = (const float*)d_in[9];
    const float* w5 = (const float*)d_in[10];
    const float* b5 = (const float*)d_in[11];
    float* out = (float*)d_out;
    int P = in_sizes[0] / 3;

    int* counts = (int*)d_ws;
    int* offsets = counts + 4096;
    int* cursor = offsets + 4104;
    int* sorted = cursor + 4096;

    hipMemsetAsync(counts, 0, 4096 * sizeof(int), stream);

    int blk = 256;
    int grd = (P + blk - 1) / blk;
    k_count<<<grd, blk, 0, stream>>>(xs, counts, out, P);
    k_scan<<<1, 64, 0, stream>>>(counts, offsets, cursor);
    k_scatter<<<grd, blk, 0, stream>>>(xs, cursor, sorted, P);
    k_mlp<<<NCELL, 128, 0, stream>>>(xs, dv, w1, b1, w2, b2, w3, b3, w4, b4, w5, b5,
                                     offsets, sorted, out, P);
}

// Round 7
// 153.108 us; speedup vs baseline: 2.1935x; 2.1935x over previous
//
#include <hip/hip_runtime.h>
#include <hip/hip_fp16.h>

#define NCELL 4096

// LDS f16 weight layout (ushort offsets; all read bases 16B-aligned)
#define W1S0 0     // wave0 slice [63][16]
#define W1S1 1008  // wave1 slice [63][16]
#define W2P  2016  // [32][40] padded (33 used)
#define W3S0 3296  // [32][16]
#define W3S1 3808
#define W4S0 4320  // [59][16]
#define W4S1 5264
#define W5P  6208  // [32][4] (3 used)
#define BB1  6336  // 32
#define BB2  6368  // 33 (pad 40)
#define BB3  6408  // 32
#define BB4  6440  // 32
#define BB5  6472  // 3 (pad 8)
#define WLTOT 6480 // 12960 B

__device__ __forceinline__ int cell_of(float x0, float x1, float x2) {
    int i0 = (int)(x0 / 0.1875f + 8.0f);
    int i1 = (int)(x1 / 0.1875f + 8.0f);
    int i2 = (int)(x2 / 0.1875f + 8.0f);
    i0 = i0 < 0 ? 0 : (i0 > 15 ? 15 : i0);
    i1 = i1 < 0 ? 0 : (i1 > 15 ? 15 : i1);
    i2 = i2 < 0 ? 0 : (i2 > 15 ? 15 : i2);
    return (i0 * 16 + i1) * 16 + i2;
}

__global__ void k_count(const float* __restrict__ xs, int* __restrict__ counts,
                        float* __restrict__ out, int P) {
    int p = blockIdx.x * blockDim.x + threadIdx.x;
    if (p >= P) return;
    float x0 = xs[p * 3 + 0], x1 = xs[p * 3 + 1], x2 = xs[p * 3 + 2];
    bool m = (fabsf(x0) < 1.5f) && (fabsf(x1) < 1.5f) && (fabsf(x2) < 1.5f);
    if (m) {
        atomicAdd(&counts[cell_of(x0, x1, x2)], 1);
    } else {
        out[p * 3 + 0] = 0.0f;
        out[p * 3 + 1] = 0.0f;
        out[p * 3 + 2] = 0.0f;
        out[3 * P + p] = 0.0f;
    }
}

__global__ void k_scan(const int* __restrict__ counts, int* __restrict__ offsets,
                       int* __restrict__ cursor) {
    int l = threadIdx.x;
    int base = l * 64;
    int s = 0;
    for (int k = 0; k < 64; k++) s += counts[base + k];
    int incl = s;
    for (int d = 1; d < 64; d <<= 1) {
        int v = __shfl_up(incl, d, 64);
        if (l >= d) incl += v;
    }
    int run = incl - s;
    for (int k = 0; k < 64; k++) {
        offsets[base + k] = run;
        cursor[base + k] = run;
        run += counts[base + k];
    }
    if (l == 63) offsets[4096] = run;
}

__global__ void k_scatter(const float* __restrict__ xs, int* __restrict__ cursor,
                          int* __restrict__ sorted, int P) {
    int p = blockIdx.x * blockDim.x + threadIdx.x;
    if (p >= P) return;
    float x0 = xs[p * 3 + 0], x1 = xs[p * 3 + 1], x2 = xs[p * 3 + 2];
    bool m = (fabsf(x0) < 1.5f) && (fabsf(x1) < 1.5f) && (fabsf(x2) < 1.5f);
    if (!m) return;
    int c = cell_of(x0, x1, x2);
    int pos = atomicAdd(&cursor[c], 1);
    sorted[pos] = p;
}

__device__ __forceinline__ unsigned int pack2(float a, float b) {
    __half2 h = __floats2half2_rn(a, b);
    return *(unsigned int*)&h;
}

// Stage a [rows][32] fp32 matrix into two per-wave [rows][16] f16 slices.
__device__ __forceinline__ void stage_slice(ushort* __restrict__ wl, int s0, int s1,
                                            const float* __restrict__ src,
                                            int n4, int tid) {
    for (int k = tid; k < n4; k += 128) {
        float4 v = ((const float4*)src)[k];
        int row = k >> 3, cg = k & 7;
        int base = ((cg >> 2) ? s1 : s0) + row * 16 + ((cg & 3) << 2);
        uint2 u;
        u.x = pack2(v.x, v.y);
        u.y = pack2(v.z, v.w);
        *(uint2*)&wl[base] = u;
    }
}

#define H2F(U16) __half2float(__ushort_as_half(U16))

#define UNFMA2(ACC, IDX, U, E)                                              \
    {                                                                       \
        __half2 _h = *(const __half2*)&(U);                                 \
        ACC[IDX] = fmaf(E, __half2float(_h.x), ACC[IDX]);                   \
        ACC[(IDX) + 1] = fmaf(E, __half2float(_h.y), ACC[(IDX) + 1]);       \
    }

// 16-wide f16 row FMA: 2x ds_read_b128 + 16 v_fma_mix
#define ROW16H(ACC, PTR, E)                                                 \
    {                                                                       \
        const uint4* _p = (const uint4*)(PTR);                              \
        uint4 _q0 = _p[0], _q1 = _p[1];                                     \
        float _e = (E);                                                     \
        UNFMA2(ACC, 0, _q0.x, _e) UNFMA2(ACC, 2, _q0.y, _e)                 \
        UNFMA2(ACC, 4, _q0.z, _e) UNFMA2(ACC, 6, _q0.w, _e)                 \
        UNFMA2(ACC, 8, _q1.x, _e) UNFMA2(ACC, 10, _q1.y, _e)                \
        UNFMA2(ACC, 12, _q1.z, _e) UNFMA2(ACC, 14, _q1.w, _e)               \
    }

// 17-wide variant for layer 2
#define ROW17H(ACC, PTR, E)                                                 \
    {                                                                       \
        const uint4* _p = (const uint4*)(PTR);                              \
        uint4 _q0 = _p[0], _q1 = _p[1];                                     \
        unsigned int _q2 = ((const unsigned int*)_p)[8];                    \
        float _e = (E);                                                     \
        UNFMA2(ACC, 0, _q0.x, _e) UNFMA2(ACC, 2, _q0.y, _e)                 \
        UNFMA2(ACC, 4, _q0.z, _e) UNFMA2(ACC, 6, _q0.w, _e)                 \
        UNFMA2(ACC, 8, _q1.x, _e) UNFMA2(ACC, 10, _q1.y, _e)                \
        UNFMA2(ACC, 12, _q1.z, _e) UNFMA2(ACC, 14, _q1.w, _e)               \
        {                                                                   \
            __half2 _h = *(const __half2*)&_q2;                             \
            ACC[16] = fmaf(_e, __half2float(_h.x), ACC[16]);                \
        }                                                                   \
    }

// One block (2 waves) per cell. f16 weights in LDS per-wave column slices
// (2x ds_read_b128 per row instead of 4); fp32 accumulate via v_fma_mix.
// Activations in per-lane LDS stride-33 slots (2-way alias, free).
__global__ void __launch_bounds__(128) k_mlp(
    const float* __restrict__ xs, const float* __restrict__ dvs,
    const float* __restrict__ w1, const float* __restrict__ b1,
    const float* __restrict__ w2, const float* __restrict__ b2,
    const float* __restrict__ w3, const float* __restrict__ b3,
    const float* __restrict__ w4, const float* __restrict__ b4,
    const float* __restrict__ w5, const float* __restrict__ b5,
    const int* __restrict__ offsets, const int* __restrict__ sorted,
    float* __restrict__ out, int P) {
    __shared__ ushort wl[WLTOT];
    __shared__ float act[64 * 33];
    int cell = blockIdx.x;
    int start = offsets[cell], end = offsets[cell + 1];
    if (start >= end) return;
    int tid = threadIdx.x;
    int lane = tid & 63;
    int wid = tid >> 6;
    int wo = wid << 4;

    // ---- stage weights fp32 -> f16 LDS
    stage_slice(wl, W1S0, W1S1, w1 + (size_t)cell * 2016, 504, tid);
    stage_slice(wl, W3S0, W3S1, w3 + (size_t)cell * 1024, 256, tid);
    stage_slice(wl, W4S0, W4S1, w4 + (size_t)cell * 1888, 472, tid);
    {
        const float* s2 = w2 + (size_t)cell * 1056;
        for (int e = tid; e < 1056; e += 128) {
            int r = e / 33, c = e - r * 33;
            wl[W2P + r * 40 + c] = __half_as_ushort(__float2half_rn(s2[e]));
        }
        const float* s5 = w5 + (size_t)cell * 96;
        for (int e = tid; e < 96; e += 128) {
            int r = e / 3, c = e - r * 3;
            wl[W5P + r * 4 + c] = __half_as_ushort(__float2half_rn(s5[e]));
        }
        if (tid < 32) wl[BB1 + tid] = __half_as_ushort(__float2half_rn(b1[(size_t)cell * 32 + tid]));
        if (tid < 33) wl[BB2 + tid] = __half_as_ushort(__float2half_rn(b2[(size_t)cell * 33 + tid]));
        if (tid >= 64 && tid < 96) wl[BB3 + tid - 64] = __half_as_ushort(__float2half_rn(b3[(size_t)cell * 32 + tid - 64]));
        if (tid >= 96) wl[BB4 + tid - 96] = __half_as_ushort(__float2half_rn(b4[(size_t)cell * 32 + tid - 96]));
        if (tid >= 60 && tid < 63) wl[BB5 + tid - 60] = __half_as_ushort(__float2half_rn(b5[(size_t)cell * 3 + tid - 60]));
    }
    __syncthreads();

    const ushort* w1s = &wl[wid ? W1S1 : W1S0];
    const ushort* w3s = &wl[wid ? W3S1 : W3S0];
    const ushort* w4s = &wl[wid ? W4S1 : W4S0];

    float* al = &act[lane * 33];

    for (int t0 = start; t0 < end; t0 += 64) {
        __syncthreads();
        int t = t0 + lane;
        bool valid = t < end;
        int idx = sorted[valid ? t : start];

        float x0 = xs[idx * 3 + 0], x1 = xs[idx * 3 + 1], x2 = xs[idx * 3 + 2];
        float d0 = dvs[idx * 3 + 0], d1 = dvs[idx * 3 + 1], d2 = dvs[idx * 3 + 2];

        float acc[17];
        float sigma = 0.0f;

        // ---- layer 1: 63 -> 32 (this wave: 16), relu; pos-enc fused
#pragma unroll
        for (int o = 0; o < 16; o++) acc[o] = H2F(wl[BB1 + wo + o]);
        ROW16H(acc, w1s + 0 * 16, x0)
        ROW16H(acc, w1s + 1 * 16, x1)
        ROW16H(acc, w1s + 2 * 16, x2)
        float pw = 1.0f;
#pragma unroll 2
        for (int j = 0; j < 10; j++) {
            float a0 = pw * x0, a1 = pw * x1, a2 = pw * x2;
            const ushort* rb = w1s + (3 + 6 * j) * 16;
            ROW16H(acc, rb + 0, __sinf(a0))
            ROW16H(acc, rb + 16, __sinf(a1))
            ROW16H(acc, rb + 32, __sinf(a2))
            ROW16H(acc, rb + 48, __cosf(a0))
            ROW16H(acc, rb + 64, __cosf(a1))
            ROW16H(acc, rb + 80, __cosf(a2))
            pw *= 2.0f;
        }
#pragma unroll
        for (int o = 0; o < 16; o++) al[wo + o] = fmaxf(acc[o], 0.0f);
        __syncthreads();

        // ---- layer 2: 32 -> 33; wave w computes cols [16w, 16w+17)
        float g[17];
#pragma unroll
        for (int k = 0; k < 17; k++) g[k] = H2F(wl[BB2 + wo + k]);
#pragma unroll 2
        for (int i = 0; i < 32; i++) {
            float e = al[i];
            ROW17H(g, &wl[W2P + i * 40 + wo], e)
        }
        __syncthreads();  // act reads done before overwrite
        if (wid == 0) {
            sigma = fmaxf(g[0], 0.0f);
#pragma unroll
            for (int k = 1; k < 17; k++) al[k - 1] = fmaxf(g[k], 0.0f);
        } else {
            // al[15] (col 16) written by both waves, bit-identical -> benign
#pragma unroll
            for (int k = 0; k < 17; k++) al[15 + k] = fmaxf(g[k], 0.0f);
        }
        __syncthreads();

        // ---- layer 3: 32 -> 32, no activation
#pragma unroll
        for (int o = 0; o < 16; o++) acc[o] = H2F(wl[BB3 + wo + o]);
#pragma unroll 2
        for (int i = 0; i < 32; i++) {
            float e = al[i];
            ROW16H(acc, w3s + i * 16, e)
        }
        __syncthreads();
#pragma unroll
        for (int o = 0; o < 16; o++) al[wo + o] = acc[o];
        __syncthreads();

        // ---- layer 4: 59 -> 32, relu; dir-enc fused
#pragma unroll
        for (int o = 0; o < 16; o++) acc[o] = H2F(wl[BB4 + wo + o]);
#pragma unroll 2
        for (int i = 0; i < 32; i++) {
            float e = al[i];
            ROW16H(acc, w4s + i * 16, e)
        }
        __syncthreads();  // act reads done
        ROW16H(acc, w4s + 32 * 16, d0)
        ROW16H(acc, w4s + 33 * 16, d1)
        ROW16H(acc, w4s + 34 * 16, d2)
        pw = 1.0f;
#pragma unroll 2
        for (int j = 0; j < 4; j++) {
            float a0 = pw * d0, a1 = pw * d1, a2 = pw * d2;
            const ushort* rb = w4s + (35 + 6 * j) * 16;
            ROW16H(acc, rb + 0, __sinf(a0))
            ROW16H(acc, rb + 16, __sinf(a1))
            ROW16H(acc, rb + 32, __sinf(a2))
            ROW16H(acc, rb + 48, __cosf(a0))
            ROW16H(acc, rb + 64, __cosf(a1))
            ROW16H(acc, rb + 80, __cosf(a2))
            pw *= 2.0f;
        }
#pragma unroll
        for (int o = 0; o < 16; o++) al[wo + o] = fmaxf(acc[o], 0.0f);
        __syncthreads();

        // ---- layer 5: 32 -> 3, sigmoid (wave 0 only)
        if (wid == 0) {
            float c0 = H2F(wl[BB5 + 0]), c1 = H2F(wl[BB5 + 1]), c2 = H2F(wl[BB5 + 2]);
#pragma unroll 4
            for (int i = 0; i < 32; i++) {
                float e = al[i];
                uint2 u = *(const uint2*)&wl[W5P + i * 4];
                __half2 ha = *(const __half2*)&u.x;
                __half2 hb = *(const __half2*)&u.y;
                c0 = fmaf(e, __half2float(ha.x), c0);
                c1 = fmaf(e, __half2float(ha.y), c1);
                c2 = fmaf(e, __half2float(hb.x), c2);
            }
            if (valid) {
                out[idx * 3 + 0] = 1.0f / (1.0f + __expf(-c0));
                out[idx * 3 + 1] = 1.0f / (1.0f + __expf(-c1));
                out[idx * 3 + 2] = 1.0f / (1.0f + __expf(-c2));
                out[3 * P + idx] = sigma;
            }
        }
    }
}

extern "C" void kernel_launch(void* const* d_in, const int* in_sizes, int n_in,
                              void* d_out, int out_size, void* d_ws, size_t ws_size,
                              hipStream_t stream) {
    const float* xs = (const float*)d_in[0];
    const float* dv = (const float*)d_in[1];
    const float* w1 = (const float*)d_in[2];
    const float* b1 = (const float*)d_in[3];
    const float* w2 = (const float*)d_in[4];
    const float* b2 = (const float*)d_in[5];
    const float* w3 = (const float*)d_in[6];
    const float* b3 = (const float*)d_in[7];
    const float* w4 = (const float*)d_in[8];
    const float* b4 = (const float*)d_in[9];
    const float* w5 = (const float*)d_in[10];
    const float* b5 = (const float*)d_in[11];
    float* out = (float*)d_out;
    int P = in_sizes[0] / 3;

    int* counts = (int*)d_ws;
    int* offsets = counts + 4096;
    int* cursor = offsets + 4104;
    int* sorted = cursor + 4096;

    hipMemsetAsync(counts, 0, 4096 * sizeof(int), stream);

    int blk = 256;
    int grd = (P + blk - 1) / blk;
    k_count<<<grd, blk, 0, stream>>>(xs, counts, out, P);
    k_scan<<<1, 64, 0, stream>>>(counts, offsets, cursor);
    k_scatter<<<grd, blk, 0, stream>>>(xs, cursor, sorted, P);
    k_mlp<<<NCELL, 128, 0, stream>>>(xs, dv, w1, b1, w2, b2, w3, b3, w4, b4, w5, b5,
                                     offsets, sorted, out, P);
}

// Round 9
// 111.058 us; speedup vs baseline: 3.0240x; 1.3786x over previous
//
#include <hip/hip_runtime.h>
#include <hip/hip_fp16.h>

#define NCELL 4096

typedef _Float16 half2_t __attribute__((ext_vector_type(2)));

__device__ __forceinline__ half2_t u2h(unsigned int u) {
    union { unsigned int u; half2_t h; } x; x.u = u; return x.h;
}
__device__ __forceinline__ unsigned int packrn(float a, float b) {
    __half2 h = __floats2half2_rn(a, b);
    union { __half2 h; unsigned int u; } x; x.h = h; return x.u;
}
// cvt_pkrtz returns __fp16 ext_vector(2); fdot2 wants _Float16 ext_vector(2).
// Same bits -> bit-cast through a union.
__device__ __forceinline__ half2_t pk2(float a, float b) {
    auto v = __builtin_amdgcn_cvt_pkrtz(a, b);
    union { decltype(v) i; half2_t o; } x; x.i = v; return x.o;
}
#define PK(a, b) pk2((a), (b))
#define FD(e2, u, acc) __builtin_amdgcn_fdot2((e2), u2h(u), (acc), false)

// 16 outputs x one row-pair: 4x ds_read_b128 + 16x v_dot2_f32_f16
#define PAIRROW16(ACC, PTR, E2)                                            \
    {                                                                      \
        const uint4* _p = (const uint4*)(PTR);                             \
        uint4 _a = _p[0], _b = _p[1], _c = _p[2], _d = _p[3];              \
        half2_t _e = (E2);                                                 \
        ACC[0] = FD(_e, _a.x, ACC[0]);  ACC[1] = FD(_e, _a.y, ACC[1]);     \
        ACC[2] = FD(_e, _a.z, ACC[2]);  ACC[3] = FD(_e, _a.w, ACC[3]);     \
        ACC[4] = FD(_e, _b.x, ACC[4]);  ACC[5] = FD(_e, _b.y, ACC[5]);     \
        ACC[6] = FD(_e, _b.z, ACC[6]);  ACC[7] = FD(_e, _b.w, ACC[7]);     \
        ACC[8] = FD(_e, _c.x, ACC[8]);  ACC[9] = FD(_e, _c.y, ACC[9]);     \
        ACC[10] = FD(_e, _c.z, ACC[10]); ACC[11] = FD(_e, _c.w, ACC[11]);  \
        ACC[12] = FD(_e, _d.x, ACC[12]); ACC[13] = FD(_e, _d.y, ACC[13]);  \
        ACC[14] = FD(_e, _d.z, ACC[14]); ACC[15] = FD(_e, _d.w, ACC[15]);  \
    }

__device__ __forceinline__ int cell_of(float x0, float x1, float x2) {
    int i0 = (int)(x0 / 0.1875f + 8.0f);
    int i1 = (int)(x1 / 0.1875f + 8.0f);
    int i2 = (int)(x2 / 0.1875f + 8.0f);
    i0 = i0 < 0 ? 0 : (i0 > 15 ? 15 : i0);
    i1 = i1 < 0 ? 0 : (i1 > 15 ? 15 : i1);
    i2 = i2 < 0 ? 0 : (i2 > 15 ? 15 : i2);
    return (i0 * 16 + i1) * 16 + i2;
}

__global__ void k_count(const float* __restrict__ xs, int* __restrict__ counts,
                        float* __restrict__ out, int P) {
    int p = blockIdx.x * blockDim.x + threadIdx.x;
    if (p >= P) return;
    float x0 = xs[p * 3 + 0], x1 = xs[p * 3 + 1], x2 = xs[p * 3 + 2];
    bool m = (fabsf(x0) < 1.5f) && (fabsf(x1) < 1.5f) && (fabsf(x2) < 1.5f);
    if (m) {
        atomicAdd(&counts[cell_of(x0, x1, x2)], 1);
    } else {
        out[p * 3 + 0] = 0.0f;
        out[p * 3 + 1] = 0.0f;
        out[p * 3 + 2] = 0.0f;
        out[3 * P + p] = 0.0f;
    }
}

__global__ void k_scan(const int* __restrict__ counts, int* __restrict__ offsets,
                       int* __restrict__ cursor) {
    int l = threadIdx.x;
    int base = l * 64;
    int s = 0;
    for (int k = 0; k < 64; k++) s += counts[base + k];
    int incl = s;
    for (int d = 1; d < 64; d <<= 1) {
        int v = __shfl_up(incl, d, 64);
        if (l >= d) incl += v;
    }
    int run = incl - s;
    for (int k = 0; k < 64; k++) {
        offsets[base + k] = run;
        cursor[base + k] = run;
        run += counts[base + k];
    }
    if (l == 63) offsets[4096] = run;
}

__global__ void k_scatter(const float* __restrict__ xs, int* __restrict__ cursor,
                          int* __restrict__ sorted, int P) {
    int p = blockIdx.x * blockDim.x + threadIdx.x;
    if (p >= P) return;
    float x0 = xs[p * 3 + 0], x1 = xs[p * 3 + 1], x2 = xs[p * 3 + 2];
    bool m = (fabsf(x0) < 1.5f) && (fabsf(x1) < 1.5f) && (fabsf(x2) < 1.5f);
    if (!m) return;
    int c = cell_of(x0, x1, x2);
    int pos = atomicAdd(&cursor[c], 1);
    sorted[pos] = p;
}

// pair p -> source rows of the 63-row encoded input (header + 3 pairs/block)
__device__ __forceinline__ void prows1(int p, int& rA, int& rB) {
    if (p == 0) { rA = 0; rB = 1; }
    else if (p == 1) { rA = 2; rB = -1; }
    else { int q = p - 2; int j = q / 3; int k = q - 3 * j; rA = 3 + 6 * j + 2 * k; rB = rA + 1; }
}
__device__ __forceinline__ void prows4(int p, int& rA, int& rB) {
    if (p < 16) { rA = 2 * p; rB = rA + 1; }
    else {
        int pd = p - 16;
        if (pd == 0) { rA = 32; rB = 33; }
        else if (pd == 1) { rA = 34; rB = -1; }
        else { int q = pd - 2; int j = q / 3; int k = q - 3 * j; rA = 35 + 6 * j + 2 * k; rB = rA + 1; }
    }
}

// LDS uint layout: W1 2x[32][16] @0 | W2 2x[16][20] @1024 | W3 2x[16][16] @1664
// | W4 2x[30][16] @2176 | W5 [16][4] @3616 | total 3680 uints
__global__ void __launch_bounds__(128) k_mlp(
    const float* __restrict__ xs, const float* __restrict__ dvs,
    const float* __restrict__ w1g, const float* __restrict__ b1g,
    const float* __restrict__ w2g, const float* __restrict__ b2g,
    const float* __restrict__ w3g, const float* __restrict__ b3g,
    const float* __restrict__ w4g, const float* __restrict__ b4g,
    const float* __restrict__ w5g, const float* __restrict__ b5g,
    const int* __restrict__ offsets, const int* __restrict__ sorted,
    float* __restrict__ out, int P) {
    __shared__ unsigned int wh[3680];
    __shared__ float bf[132];
    __shared__ float act[64 * 34];
    int cell = blockIdx.x;
    int start = offsets[cell], end = offsets[cell + 1];
    if (start >= end) return;
    int tid = threadIdx.x;
    int lane = tid & 63;
    int wid = tid >> 6;
    int wo = wid << 4;

    const float* W1 = w1g + (size_t)cell * 2016;
    const float* W2 = w2g + (size_t)cell * 1056;
    const float* W3 = w3g + (size_t)cell * 1024;
    const float* W4 = w4g + (size_t)cell * 1888;
    const float* W5 = w5g + (size_t)cell * 96;

    // ---- stage weights as row-pair-interleaved half2
    for (int e = tid; e < 1024; e += 128) {
        int s = e >> 9, pr = (e >> 4) & 31, cc = e & 15;
        int c = (s << 4) + cc;
        int rA, rB; prows1(pr, rA, rB);
        float a = W1[rA * 32 + c];
        float b = (rB >= 0) ? W1[rB * 32 + c] : 0.0f;
        wh[e] = packrn(a, b);
    }
    for (int e = tid; e < 544; e += 128) {
        int s = e / 272, q = e - s * 272;
        int pr = q / 17, k = q - pr * 17;
        int c = s * 16 + k;
        wh[1024 + s * 320 + pr * 20 + k] =
            packrn(W2[(2 * pr) * 33 + c], W2[(2 * pr + 1) * 33 + c]);
    }
    for (int e = tid; e < 512; e += 128) {
        int s = e >> 8, pr = (e >> 4) & 15, cc = e & 15;
        int c = (s << 4) + cc;
        wh[1664 + e] = packrn(W3[2 * pr * 32 + c], W3[(2 * pr + 1) * 32 + c]);
    }
    for (int e = tid; e < 960; e += 128) {
        int s = e / 480, q = e - s * 480;
        int pr = q >> 4, cc = q & 15;
        int c = (s << 4) + cc;
        int rA, rB; prows4(pr, rA, rB);
        float a = W4[rA * 32 + c];
        float b = (rB >= 0) ? W4[rB * 32 + c] : 0.0f;
        wh[2176 + s * 480 + pr * 16 + cc] = packrn(a, b);
    }
    for (int e = tid; e < 64; e += 128) {
        int pr = e >> 2, c = e & 3;
        float a = (c < 3) ? W5[2 * pr * 3 + c] : 0.0f;
        float b = (c < 3) ? W5[(2 * pr + 1) * 3 + c] : 0.0f;
        wh[3616 + e] = packrn(a, b);
    }
    for (int e = tid; e < 132; e += 128) {
        float v;
        if (e < 32) v = b1g[(size_t)cell * 32 + e];
        else if (e < 65) v = b2g[(size_t)cell * 33 + e - 32];
        else if (e < 97) v = b3g[(size_t)cell * 32 + e - 65];
        else if (e < 129) v = b4g[(size_t)cell * 32 + e - 97];
        else v = b5g[(size_t)cell * 3 + e - 129];
        bf[e] = v;
    }
    __syncthreads();

    const unsigned int* w1u = &wh[wid ? 512 : 0];
    const unsigned int* w2u = &wh[1024 + (wid ? 320 : 0)];
    const unsigned int* w3u = &wh[1664 + (wid ? 256 : 0)];
    const unsigned int* w4u = &wh[2176 + (wid ? 480 : 0)];
    const unsigned int* w5u = &wh[3616];

    float* al = &act[lane * 34];

    for (int t0 = start; t0 < end; t0 += 64) {
        __syncthreads();
        int t = t0 + lane;
        bool valid = t < end;
        int idx = sorted[valid ? t : start];

        float x0 = xs[idx * 3 + 0], x1 = xs[idx * 3 + 1], x2 = xs[idx * 3 + 2];
        float d0 = dvs[idx * 3 + 0], d1 = dvs[idx * 3 + 1], d2 = dvs[idx * 3 + 2];

        float acc[16];
        float sigma = 0.0f;

        // ---- layer 1: 63 -> 32 (this wave: 16), relu; pos-enc fused
#pragma unroll
        for (int o = 0; o < 16; o++) acc[o] = bf[0 + wo + o];
        PAIRROW16(acc, w1u + 0, PK(x0, x1))
        PAIRROW16(acc, w1u + 16, PK(x2, 0.0f))
        float pw = 1.0f;
#pragma unroll 2
        for (int j = 0; j < 10; j++) {
            float a0 = pw * x0, a1 = pw * x1, a2 = pw * x2;
            float s0 = __sinf(a0), s1 = __sinf(a1), s2 = __sinf(a2);
            float c0 = __cosf(a0), c1 = __cosf(a1), c2 = __cosf(a2);
            const unsigned int* rb = w1u + (2 + 3 * j) * 16;
            PAIRROW16(acc, rb + 0, PK(s0, s1))
            PAIRROW16(acc, rb + 16, PK(s2, c0))
            PAIRROW16(acc, rb + 32, PK(c1, c2))
            pw *= 2.0f;
        }
#pragma unroll
        for (int o = 0; o < 16; o++) al[wo + o] = fmaxf(acc[o], 0.0f);
        __syncthreads();

        // ---- layer 2: 32 -> 33; wave w computes cols [16w, 16w+17)
        float g[17];
#pragma unroll
        for (int k = 0; k < 17; k++) g[k] = bf[32 + wo + k];
#pragma unroll 2
        for (int p = 0; p < 16; p++) {
            float2 av = *(const float2*)&al[2 * p];
            half2_t e2 = PK(av.x, av.y);
            const unsigned int* ptr = w2u + p * 20;
            PAIRROW16(g, ptr, e2)
            g[16] = FD(e2, ptr[16], g[16]);
        }
        __syncthreads();  // act reads done before overwrite
        if (wid == 0) {
            sigma = fmaxf(g[0], 0.0f);
#pragma unroll
            for (int k = 1; k < 17; k++) al[k - 1] = fmaxf(g[k], 0.0f);
        } else {
            // al[15] written by both waves with bit-identical value -> benign
#pragma unroll
            for (int k = 0; k < 17; k++) al[15 + k] = fmaxf(g[k], 0.0f);
        }
        __syncthreads();

        // ---- layer 3: 32 -> 32, no activation
#pragma unroll
        for (int o = 0; o < 16; o++) acc[o] = bf[65 + wo + o];
#pragma unroll 2
        for (int p = 0; p < 16; p++) {
            float2 av = *(const float2*)&al[2 * p];
            PAIRROW16(acc, w3u + p * 16, PK(av.x, av.y))
        }
        __syncthreads();
#pragma unroll
        for (int o = 0; o < 16; o++) al[wo + o] = acc[o];
        __syncthreads();

        // ---- layer 4: 59 -> 32, relu; dir-enc fused
#pragma unroll
        for (int o = 0; o < 16; o++) acc[o] = bf[97 + wo + o];
#pragma unroll 2
        for (int p = 0; p < 16; p++) {
            float2 av = *(const float2*)&al[2 * p];
            PAIRROW16(acc, w4u + p * 16, PK(av.x, av.y))
        }
        __syncthreads();  // act reads done
        PAIRROW16(acc, w4u + 16 * 16, PK(d0, d1))
        PAIRROW16(acc, w4u + 17 * 16, PK(d2, 0.0f))
        pw = 1.0f;
#pragma unroll 2
        for (int j = 0; j < 4; j++) {
            float a0 = pw * d0, a1 = pw * d1, a2 = pw * d2;
            float s0 = __sinf(a0), s1 = __sinf(a1), s2 = __sinf(a2);
            float c0 = __cosf(a0), c1 = __cosf(a1), c2 = __cosf(a2);
            const unsigned int* rb = w4u + (18 + 3 * j) * 16;
            PAIRROW16(acc, rb + 0, PK(s0, s1))
            PAIRROW16(acc, rb + 16, PK(s2, c0))
            PAIRROW16(acc, rb + 32, PK(c1, c2))
            pw *= 2.0f;
        }
#pragma unroll
        for (int o = 0; o < 16; o++) al[wo + o] = fmaxf(acc[o], 0.0f);
        __syncthreads();

        // ---- layer 5: 32 -> 3, sigmoid (wave 0 only)
        if (wid == 0) {
            float c0 = bf[129], c1 = bf[130], c2 = bf[131];
#pragma unroll 2
            for (int p = 0; p < 16; p++) {
                float2 av = *(const float2*)&al[2 * p];
                half2_t e2 = PK(av.x, av.y);
                uint4 q = *(const uint4*)(w5u + p * 4);
                c0 = FD(e2, q.x, c0);
                c1 = FD(e2, q.y, c1);
                c2 = FD(e2, q.z, c2);
            }
            if (valid) {
                out[idx * 3 + 0] = 1.0f / (1.0f + __expf(-c0));
                out[idx * 3 + 1] = 1.0f / (1.0f + __expf(-c1));
                out[idx * 3 + 2] = 1.0f / (1.0f + __expf(-c2));
                out[3 * P + idx] = sigma;
            }
        }
    }
}

extern "C" void kernel_launch(void* const* d_in, const int* in_sizes, int n_in,
                              void* d_out, int out_size, void* d_ws, size_t ws_size,
                              hipStream_t stream) {
    const float* xs = (const float*)d_in[0];
    const float* dv = (const float*)d_in[1];
    const float* w1 = (const float*)d_in[2];
    const float* b1 = (const float*)d_in[3];
    const float* w2 = (const float*)d_in[4];
    const float* b2 = (const float*)d_in[5];
    const float* w3 = (const float*)d_in[6];
    const float* b3 = (const float*)d_in[7];
    const float* w4 = (const float*)d_in[8];
    const float* b4 = (const float*)d_in[9];
    const float* w5 = (const float*)d_in[10];
    const float* b5 = (const float*)d_in[11];
    float* out = (float*)d_out;
    int P = in_sizes[0] / 3;

    int* counts = (int*)d_ws;
    int* offsets = counts + 4096;
    int* cursor = offsets + 4104;
    int* sorted = cursor + 4096;

    hipMemsetAsync(counts, 0, 4096 * sizeof(int), stream);

    int blk = 256;
    int grd = (P + blk - 1) / blk;
    k_count<<<grd, blk, 0, stream>>>(xs, counts, out, P);
    k_scan<<<1, 64, 0, stream>>>(counts, offsets, cursor);
    k_scatter<<<grd, blk, 0, stream>>>(xs, cursor, sorted, P);
    k_mlp<<<NCELL, 128, 0, stream>>>(xs, dv, w1, b1, w2, b2, w3, b3, w4, b4, w5, b5,
                                     offsets, sorted, out, P);
}